// Round 2
// baseline (161.486 us; speedup 1.0000x reference)
//
#include <hip/hip_runtime.h>
#include <math.h>

#define EPSF 1e-8f

// native clang vectors — accepted by __builtin_nontemporal_load/store
typedef float nvec4 __attribute__((ext_vector_type(4)));
typedef int   nivec4 __attribute__((ext_vector_type(4)));

__device__ __forceinline__ float pick(nvec4 v, int i) {
    return i == 0 ? v.x : i == 1 ? v.y : i == 2 ? v.z : v.w;
}

// Inclusive suffix scan of affine maps g(x)=A+Bx across the wave.
__device__ __forceinline__ void suffix_scan64(float& A, float& B, int lane) {
#pragma unroll
    for (int d = 1; d < 64; d <<= 1) {
        float Ao = __shfl_down(A, d);
        float Bo = __shfl_down(B, d);
        if (lane + d < 64) {
            A = fmaf(B, Ao, A);
            B = B * Bo;
        }
    }
}

// Single fused kernel, ONE WAVE PER ROW (64 lanes x 16 elems = S=1024).
// No LDS, no __syncthreads, no inter-wave stitch. Block = 4 independent
// rows. Aligned 16B cover for the misaligned values stream; lane boundary
// handled by __shfl_down from the next lane's first cover vector.
// Block nb (last): sum_reward_weights on wave 0.
__global__ __launch_bounds__(256, 4)
void td_kernel(const float* __restrict__ raw_gamma,
               const float* __restrict__ raw_lambd, int lam_off,
               const float* __restrict__ values,
               const float* __restrict__ rewards,
               const int* __restrict__ dones,
               float* __restrict__ out, int B, int S)
{
    const int lane = threadIdx.x & 63;
    const int w    = threadIdx.x >> 6;
    const float gamma = fmaxf(tanhf(raw_gamma[0]), EPSF);
    const int nb = (B + 3) >> 2;              // main blocks

    if ((int)blockIdx.x == nb) {
        // ---- sum_reward_weights: wave 0, self-contained ----
        if (threadIdx.x >= 64) return;
        const int base = lane << 4;           // 16 per lane over S=1024
        float a[16], b[16];
#pragma unroll
        for (int k = 0; k < 4; ++k) {
            float4 l4 = *(const float4*)(raw_lambd + lam_off + base + 4 * k);
            float lv[4] = {l4.x, l4.y, l4.z, l4.w};
#pragma unroll
            for (int j = 0; j < 4; ++j) {
                float g1 = gamma * fmaxf(tanhf(lv[j]), EPSF);
                b[4 * k + j] = g1;
                a[4 * k + j] = gamma - g1;
            }
        }
        float A = a[15], Bc = b[15];
#pragma unroll
        for (int j = 14; j >= 0; --j) { A = fmaf(b[j], A, a[j]); Bc *= b[j]; }
        suffix_scan64(A, Bc, lane);
        float EA = __shfl_down(A, 1);
        float EB = __shfl_down(Bc, 1);
        if (lane == 63) { EA = 0.0f; EB = 1.0f; }
        float v = EA + EB;                    // applied to v_next = 1.0
        float wv[16], sum = 0.0f;
#pragma unroll
        for (int j = 15; j >= 0; --j) {
            v = fmaf(b[j], v, a[j]);
            wv[j] = fmaxf(1.0f - v, EPSF);
            sum += wv[j];
        }
#pragma unroll
        for (int d = 32; d; d >>= 1) sum += __shfl_xor(sum, d);
        float inv = 1.0f / fmaxf(sum / (float)S, EPSF);
        float* srw = out + (size_t)B * S;
#pragma unroll
        for (int j = 0; j < 16; ++j) srw[base + j] = wv[j] * inv;
        return;
    }

    // ---- lambda_returns: one wave per row ----
    const int r = ((int)blockIdx.x << 2) + w;
    if (r >= B) return;
    const int t0 = lane << 4;                 // 16 elements per lane
    const size_t rb = (size_t)r * (S + 1);

    // Issue all stream loads up-front (coalesced per cache line set).
    nvec4 r4[4]; nivec4 d4[4];
    const nvec4*  rp = (const nvec4*)(rewards + (size_t)r * S + t0);
    const nivec4* dp = (const nivec4*)(dones + (size_t)r * S + t0);
#pragma unroll
    for (int k = 0; k < 4; ++k) {
        r4[k] = __builtin_nontemporal_load(rp + k);
        d4[k] = __builtin_nontemporal_load(dp + k);
    }

    const int sh = (r + 1) & 3;               // (rb + t0 + 1) & 3, wave-uniform
    const size_t E  = rb + t0 + 1;            // first needed v element
    const size_t A0 = E - sh;                 // 16B-aligned cover start
    nvec4 m[4];
#pragma unroll
    for (int k = 0; k < 4; ++k)
        m[k] = __builtin_nontemporal_load((const nvec4*)(values + A0) + k);
    size_t A0t = A0 + 16;                     // tail (4 elems past cover)
    const size_t last4 = (size_t)B * (S + 1) - 4;
    if (A0t > last4) A0t = last4;             // clamp (only matters when sh==0, unused)
    nvec4 t4 = __builtin_nontemporal_load((const nvec4*)(values + A0t));
    const int delta = (int)(A0 + 16 - A0t);
    float vS = values[rb + S];

    // λ coefficients: each lane tanh's only its 16 values (aligned float4).
    float g1v[16];
#pragma unroll
    for (int k = 0; k < 4; ++k) {
        float4 l4 = *(const float4*)(raw_lambd + lam_off + t0 + 4 * k);
        g1v[4 * k + 0] = gamma * fmaxf(tanhf(l4.x), EPSF);
        g1v[4 * k + 1] = gamma * fmaxf(tanhf(l4.y), EPSF);
        g1v[4 * k + 2] = gamma * fmaxf(tanhf(l4.z), EPSF);
        g1v[4 * k + 3] = gamma * fmaxf(tanhf(l4.w), EPSF);
    }

    // Reconstruct v_{t+1}..v_{t+16} from the aligned cover.
    float cov[16] = {m[0].x, m[0].y, m[0].z, m[0].w,
                     m[1].x, m[1].y, m[1].z, m[1].w,
                     m[2].x, m[2].y, m[2].z, m[2].w,
                     m[3].x, m[3].y, m[3].z, m[3].w};
    float n0 = __shfl_down(m[0].x, 1);
    float n1 = __shfl_down(m[0].y, 1);
    float n2 = __shfl_down(m[0].z, 1);
    if (lane == 63) {
        n0 = pick(t4, delta);
        n1 = pick(t4, delta + 1 > 3 ? 3 : delta + 1);
        n2 = pick(t4, delta + 2 > 3 ? 3 : delta + 2);
    }
    float vn[16];
    if (sh == 0) {
#pragma unroll
        for (int i = 0; i < 16; ++i) vn[i] = cov[i];
    } else if (sh == 1) {
#pragma unroll
        for (int i = 0; i < 15; ++i) vn[i] = cov[i + 1];
        vn[15] = n0;
    } else if (sh == 2) {
#pragma unroll
        for (int i = 0; i < 14; ++i) vn[i] = cov[i + 2];
        vn[14] = n0; vn[15] = n1;
    } else {
#pragma unroll
        for (int i = 0; i < 13; ++i) vn[i] = cov[i + 3];
        vn[13] = n0; vn[14] = n1; vn[15] = n2;
    }

    // Unpack streams with static indices.
    float rr[16]; int di[16];
#pragma unroll
    for (int k = 0; k < 4; ++k) {
        rr[4 * k + 0] = r4[k].x; rr[4 * k + 1] = r4[k].y;
        rr[4 * k + 2] = r4[k].z; rr[4 * k + 3] = r4[k].w;
        di[4 * k + 0] = d4[k].x; di[4 * k + 1] = d4[k].y;
        di[4 * k + 2] = d4[k].z; di[4 * k + 3] = d4[k].w;
    }

    // Affine coefficients: ret_t = a_t + b_t * ret_{t+1}
    float a[16], b[16];
#pragma unroll
    for (int j = 0; j < 16; ++j) {
        float ndn = 1.0f - (float)di[j];
        b[j] = g1v[j] * ndn;
        a[j] = fmaf((gamma - g1v[j]) * vn[j], ndn, rr[j]);
    }

    // Lane-local composite of 16 maps, then one 64-lane suffix scan.
    float A = a[15], Bc = b[15];
#pragma unroll
    for (int j = 14; j >= 0; --j) { A = fmaf(b[j], A, a[j]); Bc *= b[j]; }
    suffix_scan64(A, Bc, lane);
    float EA = __shfl_down(A, 1);
    float EB = __shfl_down(Bc, 1);
    if (lane == 63) { EA = 0.0f; EB = 1.0f; }

    // Carry for this lane: ret at t0+16, then the 16-step local recurrence.
    float x = fmaf(EB, vS, EA);
    float o[16];
    o[15] = fmaf(b[15], x, a[15]);
#pragma unroll
    for (int j = 14; j >= 0; --j) o[j] = fmaf(b[j], o[j + 1], a[j]);

    nvec4* op = (nvec4*)(out + (size_t)r * S + t0);
#pragma unroll
    for (int k = 0; k < 4; ++k) {
        nvec4 ov = {o[4 * k], o[4 * k + 1], o[4 * k + 2], o[4 * k + 3]};
        __builtin_nontemporal_store(ov, op + k);
    }
}

extern "C" void kernel_launch(void* const* d_in, const int* in_sizes, int n_in,
                              void* d_out, int out_size, void* d_ws, size_t ws_size,
                              hipStream_t stream) {
    const float* raw_gamma = (const float*)d_in[0];
    const float* raw_lambd = (const float*)d_in[1];
    const float* values    = (const float*)d_in[2];
    const float* rewards   = (const float*)d_in[3];
    const int*   dones     = (const int*)d_in[4];
    float* out = (float*)d_out;

    int n_v = in_sizes[2];           // B*(S+1)
    int n_r = in_sizes[3];           // B*S
    int B = n_v - n_r;               // 8192
    int S = n_r / B;                 // 1024
    int lam_off = in_sizes[1] - S;

    int nb = (B + 3) >> 2;           // 4 rows per block (one per wave)
    td_kernel<<<nb + 1, 256, 0, stream>>>(
        raw_gamma, raw_lambd, lam_off, values, rewards, dones, out, B, S);
}

// Round 3
// 141.468 us; speedup vs baseline: 1.1415x; 1.1415x over previous
//
#include <hip/hip_runtime.h>
#include <math.h>

#define EPSF 1e-8f

// native clang vectors — accepted by __builtin_nontemporal_load/store
typedef float nvec4 __attribute__((ext_vector_type(4)));
typedef int   nivec4 __attribute__((ext_vector_type(4)));

__device__ __forceinline__ float pick(nvec4 v, int i) {
    return i == 0 ? v.x : i == 1 ? v.y : i == 2 ? v.z : v.w;
}

// Inclusive suffix scan of affine maps g(x)=A+Bx across the wave.
__device__ __forceinline__ void suffix_scan64(float& A, float& B, int lane) {
#pragma unroll
    for (int d = 1; d < 64; d <<= 1) {
        float Ao = __shfl_down(A, d);
        float Bo = __shfl_down(B, d);
        if (lane + d < 64) {
            A = fmaf(B, Ao, A);
            B = B * Bo;
        }
    }
}

// Persistent-4-row version of the round-0 structure.
// Block b < nb: rows 4b..4b+3, processed sequentially by all 4 waves
// (wave c = chunk c of 256 within the row; 16B/lane fully coalesced).
// Register double-buffer: row i+1's stream loads are issued BEFORE row i's
// scan/barrier/store, so HBM latency overlaps compute. LDS stitch is
// double-buffered by row parity (one __syncthreads per row, max skew 1).
// λ tanh coefficients hoisted out of the row loop. Block nb: srw on wave 0.
__global__ __launch_bounds__(256, 4)
void td_kernel(const float* __restrict__ raw_gamma,
               const float* __restrict__ raw_lambd, int lam_off,
               const float* __restrict__ values,
               const float* __restrict__ rewards,
               const int* __restrict__ dones,
               float* __restrict__ out, int B, int S)
{
    __shared__ float sA[2][4], sB[2][4];
    const int lane = threadIdx.x & 63;
    const int c    = threadIdx.x >> 6;        // chunk 0..3
    const int nb   = B >> 2;                  // main blocks (B divisible by 4)

    if ((int)blockIdx.x == nb) {
        // ---- sum_reward_weights: wave 0, self-contained ----
        if (threadIdx.x >= 64) return;
        const float gamma = fmaxf(tanhf(raw_gamma[0]), EPSF);
        const int base = lane << 4;           // 16 per lane over S=1024
        float a[16], b[16];
#pragma unroll
        for (int k = 0; k < 4; ++k) {
            float4 l4 = *(const float4*)(raw_lambd + lam_off + base + 4 * k);
            float lv[4] = {l4.x, l4.y, l4.z, l4.w};
#pragma unroll
            for (int j = 0; j < 4; ++j) {
                float g1 = gamma * fmaxf(tanhf(lv[j]), EPSF);
                b[4 * k + j] = g1;
                a[4 * k + j] = gamma - g1;
            }
        }
        float A = a[15], Bc = b[15];
#pragma unroll
        for (int j = 14; j >= 0; --j) { A = fmaf(b[j], A, a[j]); Bc *= b[j]; }
        suffix_scan64(A, Bc, lane);
        float EA = __shfl_down(A, 1);
        float EB = __shfl_down(Bc, 1);
        if (lane == 63) { EA = 0.0f; EB = 1.0f; }
        float v = EA + EB;                    // applied to v_next = 1.0
        float w[16], sum = 0.0f;
#pragma unroll
        for (int j = 15; j >= 0; --j) {
            v = fmaf(b[j], v, a[j]);
            w[j] = fmaxf(1.0f - v, EPSF);
            sum += w[j];
        }
#pragma unroll
        for (int d = 32; d; d >>= 1) sum += __shfl_xor(sum, d);
        float inv = 1.0f / fmaxf(sum / (float)S, EPSF);
        float* srw = out + (size_t)B * S;
#pragma unroll
        for (int j = 0; j < 16; ++j) srw[base + j] = w[j] * inv;
        return;
    }

    // ---- lambda_returns: 4 rows per block, register-prefetch pipeline ----
    const float gamma = fmaxf(tanhf(raw_gamma[0]), EPSF);
    const int C  = S >> 2;                    // 256
    const int t0 = c * C + (lane << 2);

    // λ coefficients: identical for all 4 rows — hoist out of the loop.
    float4 l4 = *(const float4*)(raw_lambd + lam_off + t0);
    float lv[4] = {l4.x, l4.y, l4.z, l4.w};
    float g1v[4], av[4];
#pragma unroll
    for (int j = 0; j < 4; ++j) {
        g1v[j] = gamma * fmaxf(tanhf(lv[j]), EPSF);
        av[j]  = gamma - g1v[j];
    }

    const int r0 = (int)blockIdx.x << 2;
    const size_t last4 = (size_t)B * (S + 1) - 4;

    // double-buffered per-row stream state
    nvec4  r4[2]; nivec4 d4[2]; nvec4 m4[2], t4[2];
    float  vS[2]; int dlt[2];

#define ISSUE(BUF, RR) do {                                                     \
        const int _r = (RR);                                                    \
        r4[BUF] = __builtin_nontemporal_load(                                   \
            (const nvec4*)(rewards + (size_t)_r * S + t0));                     \
        d4[BUF] = __builtin_nontemporal_load(                                   \
            (const nivec4*)(dones + (size_t)_r * S + t0));                      \
        const size_t _rb = (size_t)_r * (S + 1);                                \
        const int _sh = (_r + 1) & 3;                                           \
        const size_t _A0 = _rb + (size_t)c * C + 1 - _sh;                       \
        m4[BUF] = __builtin_nontemporal_load((const nvec4*)(values + _A0) + lane); \
        size_t _A0t = _A0 + 256;                                                \
        if (_A0t > last4) _A0t = last4;                                         \
        t4[BUF] = __builtin_nontemporal_load((const nvec4*)(values + _A0t));    \
        dlt[BUF] = (int)(_A0 + 256 - _A0t);                                     \
        vS[BUF] = values[_rb + S];                                              \
    } while (0)

    ISSUE(0, r0);                             // prologue

#pragma unroll
    for (int i = 0; i < 4; ++i) {
        const int cur = i & 1;
        const int r   = r0 + i;
        if (i < 3) ISSUE(cur ^ 1, r + 1);     // prefetch next row NOW

        // Reconstruct v_{t+1}..v_{t+4} from the aligned cover.
        const int sh = (r + 1) & 3;           // wave-uniform
        float n0 = __shfl_down(m4[cur].x, 1);
        float n1 = __shfl_down(m4[cur].y, 1);
        float n2 = __shfl_down(m4[cur].z, 1);
        if (lane == 63) {
            const int dd = dlt[cur];
            n0 = pick(t4[cur], dd);
            n1 = pick(t4[cur], dd + 1 > 3 ? 3 : dd + 1);
            n2 = pick(t4[cur], dd + 2 > 3 ? 3 : dd + 2);
        }
        float vn0, vn1, vn2, vn3;
        if (sh == 0)      { vn0 = m4[cur].x; vn1 = m4[cur].y; vn2 = m4[cur].z; vn3 = m4[cur].w; }
        else if (sh == 1) { vn0 = m4[cur].y; vn1 = m4[cur].z; vn2 = m4[cur].w; vn3 = n0; }
        else if (sh == 2) { vn0 = m4[cur].z; vn1 = m4[cur].w; vn2 = n0;        vn3 = n1; }
        else              { vn0 = m4[cur].w; vn1 = n0;        vn2 = n1;        vn3 = n2; }

        // Affine coefficients: ret_t = a_t + b_t * ret_{t+1}
        float vn[4] = {vn0, vn1, vn2, vn3};
        float rr[4] = {r4[cur].x, r4[cur].y, r4[cur].z, r4[cur].w};
        int   di[4] = {d4[cur].x, d4[cur].y, d4[cur].z, d4[cur].w};
        float a[4], b[4];
#pragma unroll
        for (int j = 0; j < 4; ++j) {
            float ndn = 1.0f - (float)di[j];
            b[j] = g1v[j] * ndn;
            a[j] = fmaf(av[j] * vn[j], ndn, rr[j]);
        }

        // Lane-local composite of 4 maps, then one 64-lane suffix scan.
        float A = a[3], Bc = b[3];
#pragma unroll
        for (int j = 2; j >= 0; --j) { A = fmaf(b[j], A, a[j]); Bc *= b[j]; }
        suffix_scan64(A, Bc, lane);
        float EA = __shfl_down(A, 1);
        float EB = __shfl_down(Bc, 1);
        if (lane == 63) { EA = 0.0f; EB = 1.0f; }
        if (lane == 0) { sA[cur][c] = A; sB[cur][c] = Bc; }
        __syncthreads();                      // one barrier per row

        // Carry into this chunk: apply later chunks' composites to v_S.
        float x = vS[cur];
#pragma unroll
        for (int j = 3; j >= 1; --j)
            if (j > c) x = fmaf(sB[cur][j], x, sA[cur][j]);  // block-uniform per wave

        float xi = fmaf(EB, x, EA);           // ret at t0+4
        float o3 = fmaf(b[3], xi, a[3]);
        float o2 = fmaf(b[2], o3, a[2]);
        float o1 = fmaf(b[1], o2, a[1]);
        float o0 = fmaf(b[0], o1, a[0]);
        nvec4 ov = {o0, o1, o2, o3};
        __builtin_nontemporal_store(ov, (nvec4*)(out + (size_t)r * S + t0));
    }
#undef ISSUE
}

extern "C" void kernel_launch(void* const* d_in, const int* in_sizes, int n_in,
                              void* d_out, int out_size, void* d_ws, size_t ws_size,
                              hipStream_t stream) {
    const float* raw_gamma = (const float*)d_in[0];
    const float* raw_lambd = (const float*)d_in[1];
    const float* values    = (const float*)d_in[2];
    const float* rewards   = (const float*)d_in[3];
    const int*   dones     = (const int*)d_in[4];
    float* out = (float*)d_out;

    int n_v = in_sizes[2];           // B*(S+1)
    int n_r = in_sizes[3];           // B*S
    int B = n_v - n_r;               // 8192
    int S = n_r / B;                 // 1024
    int lam_off = in_sizes[1] - S;

    int nb = B >> 2;                 // 4 rows per block
    td_kernel<<<nb + 1, 256, 0, stream>>>(
        raw_gamma, raw_lambd, lam_off, values, rewards, dones, out, B, S);
}